// Round 1
// baseline (6636.432 us; speedup 1.0000x reference)
//
#include <hip/hip_runtime.h>
#include <cstdint>

#define Qn   515
#define QP   520          // padded cols (8*65)
#define Bn   256
#define Tn   512
#define OQ   516
#define EPSc 1e-16f
#define NSL  65           // cols per block slice
#define NT   5            // 16-wide n tiles per slice (80, masked >=65)
#define KT   34           // 16-deep k tiles (544)
#define USTR 552          // ushort stride of ustage row (1104 B)
#define NGRP 32
#define NBLK 8

// workspace layout (bytes)
#define WS_AMAT 0
#define WS_INIT (544*520*4)                 // 1,131,520
#define WS_UBUF (WS_INIT + 5120)            // 1,136,640
#define WS_PSUM (WS_UBUF + 2*NGRP*8*QP*4)   // + 1,064,960 = 2,201,600
#define WS_ARR  (WS_PSUM + 2*NGRP*8*8*4)    // + 16,384   = 2,217,984
#define WS_TOTAL (WS_ARR + 128)

// LDS layout (bytes)
#define L_FRAG 0
#define L_UST  87040
#define L_USL  (87040 + 17664)      // 104,704
#define L_SIG  (L_USL + 2176)       // 106,880
#define LDS_TOTAL (L_SIG + 96)      // 106,976

typedef float f32x4 __attribute__((ext_vector_type(4)));
typedef short s16x4 __attribute__((ext_vector_type(4)));

__device__ __forceinline__ unsigned bfbits(float x) {
    unsigned u = __builtin_bit_cast(unsigned, x);
    unsigned r = u + 0x7FFFu + ((u >> 16) & 1u);
    return r >> 16;
}

__global__ void prep_A(const float* __restrict__ logA, float* __restrict__ AMAT) {
    __shared__ float red[4];
    __shared__ float srow[Qn];
    int row = blockIdx.x, tid = threadIdx.x;
    if (row >= Qn) {  // pad rows 515..543 -> zero
        for (int c = tid; c < QP; c += 256) AMAT[(size_t)row*QP + c] = 0.f;
        return;
    }
    float mx = -1e30f;
    for (int c = tid; c < Qn; c += 256) { float x = logA[(size_t)row*Qn + c]; srow[c] = x; mx = fmaxf(mx, x); }
#pragma unroll
    for (int o = 32; o > 0; o >>= 1) mx = fmaxf(mx, __shfl_xor(mx, o));
    if ((tid & 63) == 0) red[tid >> 6] = mx;
    __syncthreads();
    mx = fmaxf(fmaxf(red[0], red[1]), fmaxf(red[2], red[3]));
    __syncthreads();
    float sm = 0.f;
    for (int c = tid; c < Qn; c += 256) sm += __expf(srow[c] - mx);
#pragma unroll
    for (int o = 32; o > 0; o >>= 1) sm += __shfl_xor(sm, o);
    if ((tid & 63) == 0) red[tid >> 6] = sm;
    __syncthreads();
    float inv = 1.f / (red[0] + red[1] + red[2] + red[3]);
    for (int c = tid; c < QP; c += 256)
        AMAT[(size_t)row*QP + c] = (c < Qn) ? __expf(srow[c] - mx) * inv : 0.f;
}

__global__ void prep_init(const float* __restrict__ il, float* __restrict__ INITD) {
    __shared__ float red[4];
    __shared__ float srow[Qn];
    int tid = threadIdx.x;
    float mx = -1e30f;
    for (int c = tid; c < Qn; c += 256) { float x = il[c]; srow[c] = x; mx = fmaxf(mx, x); }
#pragma unroll
    for (int o = 32; o > 0; o >>= 1) mx = fmaxf(mx, __shfl_xor(mx, o));
    if ((tid & 63) == 0) red[tid >> 6] = mx;
    __syncthreads();
    mx = fmaxf(fmaxf(red[0], red[1]), fmaxf(red[2], red[3]));
    __syncthreads();
    float sm = 0.f;
    for (int c = tid; c < Qn; c += 256) sm += __expf(srow[c] - mx);
#pragma unroll
    for (int o = 32; o > 0; o >>= 1) sm += __shfl_xor(sm, o);
    if ((tid & 63) == 0) red[tid >> 6] = sm;
    __syncthreads();
    float inv = 1.f / (red[0] + red[1] + red[2] + red[3]);
    for (int c = tid; c < QP; c += 256)
        INITD[c] = (c < Qn) ? __expf(srow[c] - mx) * inv : 0.f;
}

__global__ void __launch_bounds__(256, 1)
hmm_fwd(const float* __restrict__ E, const float* __restrict__ AMAT,
        const float* __restrict__ INITD, float* __restrict__ out,
        float* __restrict__ ubuf, float* __restrict__ psum,
        unsigned* __restrict__ arrive)
{
    extern __shared__ char smem[];
    uint2*  frag   = (uint2*)(smem + L_FRAG);            // [NT*KT*64]
    unsigned short* ustage = (unsigned short*)(smem + L_UST);  // [16][USTR]
    float*  usl    = (float*)(smem + L_USL);             // [8][68]
    float*  sig    = (float*)(smem + L_SIG);             // [8]
    float*  invs   = sig + 8;                            // [8]
    float*  lsig   = sig + 16;                           // [8]

    const int tid  = threadIdx.x;
    const int lane = tid & 63;
    const int wv   = tid >> 6;
    const int bid  = blockIdx.x;
    const int g    = bid & 31;     // group (same XCD for all its 8 blocks under rr dispatch)
    const int j    = bid >> 5;     // column-slice index within group
    const int b0   = g * 8;
    const int q0   = j * NSL;

    // ---- one-time: pack A column-slice into LDS as MFMA B-fragments ----
    for (int f = tid; f < NT*KT*64; f += 256) {
        int tile = f >> 6, l = f & 63;
        int nt = tile / KT, kt = tile - nt*KT;
        int col = q0 + nt*16 + (l & 15);
        int kb  = kt*16 + ((l >> 4) << 2);
        float v0 = 0.f, v1 = 0.f, v2 = 0.f, v3 = 0.f;
        if (col < QP) {
            const float* ap = AMAT + (size_t)kb*QP + col;
            v0 = ap[0]; v1 = ap[QP]; v2 = ap[2*QP]; v3 = ap[3*QP];
        }
        uint2 pk;
        pk.x = bfbits(v0) | (bfbits(v1) << 16);
        pk.y = bfbits(v2) | (bfbits(v3) << 16);
        frag[f] = pk;
    }
    for (int i = tid; i < 16*USTR/2; i += 256) ((unsigned*)ustage)[i] = 0u;
    float llreg = 0.f;
    __syncthreads();

    // ---- per-thread E-offset map matching MFMA D-lane layout ----
    const int ntn = (wv == 0) ? 2 : 1;
    const int nts0 = wv;
    int eoff[2][4];
#pragma unroll
    for (int sl = 0; sl < 2; ++sl) {
#pragma unroll
        for (int r = 0; r < 4; ++r) {
            int nt  = sl ? 4 : nts0;
            int row = ((lane >> 4) << 2) + r;
            int col = nt*16 + (lane & 15);
            int q   = q0 + col;
            bool ok = (lane < 32) && (col < NSL) && (q < Qn) && (sl < ntn);
            eoff[sl][r] = ok ? ((b0 + row)*Qn + q) : -1;
        }
    }

    auto rowsum_store = [&](int wb) {
        int half = lane >> 5, c = lane & 31;
        int row = wv*2 + half;
        float v = usl[row*68 + c] + usl[row*68 + c + 32];
        if (c == 0) v += usl[row*68 + 64];
#pragma unroll
        for (int o = 16; o > 0; o >>= 1) v += __shfl_xor(v, o);
        if (c == 0)
            __hip_atomic_store(&psum[(((size_t)wb*NGRP + g)*8 + row)*8 + j], v,
                               __ATOMIC_RELAXED, __HIP_MEMORY_SCOPE_AGENT);
        for (int p = tid; p < 8*NSL; p += 256) {
            int rw = p / NSL, cl = p - rw*NSL;
            int q = q0 + cl;
            if (q < Qn)
                __hip_atomic_store(&ubuf[(((size_t)wb*NGRP + g)*8 + rw)*QP + q],
                                   usl[rw*68 + cl],
                                   __ATOMIC_RELAXED, __HIP_MEMORY_SCOPE_AGENT);
        }
        __syncthreads();   // drains all vmem stores of the block before release
        if (tid == 0)
            __hip_atomic_fetch_add(&arrive[g], 1u, __ATOMIC_RELEASE, __HIP_MEMORY_SCOPE_AGENT);
    };

    auto read_phase = [&](int rb, int tOut) {
        // partial sums -> sigma (issued first, overlaps u loads)
        float ss = 0.f;
        if (tid < 8) {
            const float* pp = psum + (((size_t)rb*NGRP + g)*8 + tid)*8;
#pragma unroll
            for (int jj = 0; jj < 8; ++jj)
                ss += __hip_atomic_load(&pp[jj], __ATOMIC_RELAXED, __HIP_MEMORY_SCOPE_AGENT);
        }
        // full u rows into registers
        float ur0[9], ur1[9];
        const float* ub = ubuf + (((size_t)rb*NGRP + g)*8)*QP;
#pragma unroll
        for (int it = 0; it < 9; ++it) {
            int p = tid + it*256;
            bool ok = p < 8*260;
            int row = p / 260, kp = p - row*260;
            int idx = ok ? (row*QP + kp*2) : 0;
            ur0[it] = ok ? __hip_atomic_load(&ub[idx],   __ATOMIC_RELAXED, __HIP_MEMORY_SCOPE_AGENT) : 0.f;
            ur1[it] = ok ? __hip_atomic_load(&ub[idx+1], __ATOMIC_RELAXED, __HIP_MEMORY_SCOPE_AGENT) : 0.f;
        }
        if (tid < 8) {
            sig[tid]  = ss;
            invs[tid] = 1.f / ss;
            float ls  = __logf(ss);
            lsig[tid] = ls;
            llreg += ls;
            if (j == 0) out[((size_t)(b0 + tid)*Tn + tOut)*OQ + Qn] = llreg;
        }
        __syncthreads();
        // normalize -> bf16 stage + write log-outputs for own slice
#pragma unroll
        for (int it = 0; it < 9; ++it) {
            int p = tid + it*256;
            if (p < 8*260) {
                int row = p / 260, kp = p - row*260;
                int k = kp*2;
                float iv = invs[row];
                float a0 = ur0[it]*iv, a1 = ur1[it]*iv;
                ((unsigned*)ustage)[row*(USTR/2) + kp] = bfbits(a0) | (bfbits(a1) << 16);
                int c0 = k - q0;
                if (c0 >= 0 && c0 < NSL && k < Qn)
                    out[((size_t)(b0+row)*Tn + tOut)*OQ + k]   = __logf(ur0[it]) - lsig[row];
                int c1 = c0 + 1;
                if (c1 >= 0 && c1 < NSL && (k+1) < Qn)
                    out[((size_t)(b0+row)*Tn + tOut)*OQ + k+1] = __logf(ur1[it]) - lsig[row];
            }
        }
        __syncthreads();
    };

    // ---- t = 0 : u0 = max(E0,eps) * max(init,eps) ----
    {
        for (int p = tid; p < 8*NSL; p += 256) {
            int row = p / NSL, col = p - row*NSL;
            int q = q0 + col;
            float uv = 0.f;
            if (q < Qn) {
                float e  = fmaxf(E[(size_t)(b0+row)*Qn + q], EPSc);
                float r0 = fmaxf(INITD[q], EPSc);
                uv = e * r0;
            }
            usl[row*68 + col] = uv;
        }
        __syncthreads();
        rowsum_store(0);
    }

    // ---- main loop ----
    unsigned target = 8;
    for (int s = 1; s < Tn; ++s) {
        // prefetch E_s (issued before the spin so latency hides under it)
        float ev[2][4];
        size_t ebase = (size_t)s * Bn * Qn;
#pragma unroll
        for (int sl = 0; sl < 2; ++sl)
#pragma unroll
            for (int r = 0; r < 4; ++r)
                ev[sl][r] = (eoff[sl][r] >= 0) ? E[ebase + eoff[sl][r]] : 0.f;

        if (tid == 0) {
            while (__hip_atomic_load(&arrive[g], __ATOMIC_ACQUIRE, __HIP_MEMORY_SCOPE_AGENT) < target)
                __builtin_amdgcn_s_sleep(1);
        }
        __syncthreads();
        target += 8;

        read_phase((s-1) & 1, s-1);

        // MFMA: R-chunk = a_{s-1} (16xK, rows 8..15 zero) @ Aslice (KxN)
        f32x4 acc0 = {0.f,0.f,0.f,0.f}, acc1 = {0.f,0.f,0.f,0.f};
        {
            const unsigned short* urow = ustage + (lane & 15)*USTR + ((lane >> 4) << 2);
            const uint2* f0 = frag + (size_t)(nts0*KT)*64 + lane;
            const uint2* f1 = frag + (size_t)(4*KT)*64 + lane;
#pragma unroll 2
            for (int kt = 0; kt < KT; ++kt) {
                uint2 au = *(const uint2*)(urow + kt*16);
                s16x4 af = __builtin_bit_cast(s16x4, au);
                s16x4 bf0 = __builtin_bit_cast(s16x4, f0[kt*64]);
                acc0 = __builtin_amdgcn_mfma_f32_16x16x16bf16_1k(af, bf0, acc0, 0, 0, 0);
                if (ntn == 2) {
                    s16x4 bf1 = __builtin_bit_cast(s16x4, f1[kt*64]);
                    acc1 = __builtin_amdgcn_mfma_f32_16x16x16bf16_1k(af, bf1, acc1, 0, 0, 0);
                }
            }
        }
        // epilogue: u_s = max(E,eps) * max(R,eps)
        if (lane < 32) {
#pragma unroll
            for (int r = 0; r < 4; ++r) {
                int row = ((lane >> 4) << 2) + r;
                {
                    int col = nts0*16 + (lane & 15);
                    if (col < NSL) {
                        float R = fmaxf(acc0[r], EPSc);
                        int q = q0 + col;
                        float uv = (q < Qn) ? fmaxf(ev[0][r], EPSc) * R : 0.f;
                        usl[row*68 + col] = uv;
                    }
                }
                if (ntn == 2) {
                    int col = 64 + (lane & 15);
                    if (col < NSL) {
                        float R = fmaxf(acc1[r], EPSc);
                        int q = q0 + col;
                        float uv = (q < Qn) ? fmaxf(ev[1][r], EPSc) * R : 0.f;
                        usl[row*68 + col] = uv;
                    }
                }
            }
        }
        __syncthreads();
        rowsum_store(s & 1);
    }

    // ---- tail: emit outputs for t = 511 ----
    if (tid == 0) {
        while (__hip_atomic_load(&arrive[g], __ATOMIC_ACQUIRE, __HIP_MEMORY_SCOPE_AGENT) < target)
            __builtin_amdgcn_s_sleep(1);
    }
    __syncthreads();
    read_phase((Tn-1) & 1, Tn-1);
}

extern "C" void kernel_launch(void* const* d_in, const int* in_sizes, int n_in,
                              void* d_out, int out_size, void* d_ws, size_t ws_size,
                              hipStream_t stream) {
    (void)in_sizes; (void)n_in; (void)out_size;
    if (ws_size < (size_t)WS_TOTAL) return;   // workspace too small: bail loudly

    const float* E    = (const float*)d_in[0];
    const float* logA = (const float*)d_in[1];
    const float* il   = (const float*)d_in[2];
    float* out = (float*)d_out;
    char*  ws  = (char*)d_ws;

    float*    AMAT   = (float*)(ws + WS_AMAT);
    float*    INITD  = (float*)(ws + WS_INIT);
    float*    ubuf   = (float*)(ws + WS_UBUF);
    float*    psum   = (float*)(ws + WS_PSUM);
    unsigned* arrive = (unsigned*)(ws + WS_ARR);

    // zero exchange buffers + arrive counters (must be 0 at every launch)
    hipMemsetAsync(ws + WS_UBUF, 0, WS_TOTAL - WS_UBUF, stream);

    prep_A<<<544, 256, 0, stream>>>(logA, AMAT);
    prep_init<<<1, 256, 0, stream>>>(il, INITD);

    static_assert(LDS_TOTAL < 160*1024, "LDS budget");
    hipFuncSetAttribute(reinterpret_cast<const void*>(hmm_fwd),
                        hipFuncAttributeMaxDynamicSharedMemorySize, LDS_TOTAL);
    hmm_fwd<<<256, 256, LDS_TOTAL, stream>>>(E, AMAT, INITD, out, ubuf, psum, arrive);
}

// Round 2
// 3291.751 us; speedup vs baseline: 2.0161x; 2.0161x over previous
//
#include <hip/hip_runtime.h>
#include <cstdint>

#define Qn   515
#define QP   520          // padded cols of AMAT
#define QP2  528          // padded exchange width (8*66)
#define Bn   256
#define Tn   512
#define OQ   516
#define EPSc 1e-16f
#define NSL  65           // real cols per block slice
#define NT   5            // 16-wide n tiles per slice (80, masked >=65)
#define KT   33           // 528/16 k tiles over padded k space
#define KTA  17           // split-K first chunk
#define USTR 532          // ushorts per ustage row (1064B: 8B-aligned, bank stride 10)
#define NGRP 32
#define NBLK 8

// workspace layout (bytes)
#define WS_AMAT 0
#define WS_INIT (544*520*4)                   // 1,131,520
#define WS_UBUF (WS_INIT + 5120)              // 1,136,640 (8B aligned)
#define WS_PSUM (WS_UBUF + 2*NGRP*8*QP2*4)    // +1,081,344
#define WS_FLAG (WS_PSUM + 2*NGRP*8*8*4)      // +16,384
#define WS_TOTAL (WS_FLAG + NGRP*NBLK*64)     // +16,384 = 2,250,752

// LDS layout (bytes)
#define L_FRAG 0
#define L_UST  (NT*KT*64*8)                   // 84,480
#define L_USL  (L_UST + 16*USTR*2)            // +17,024 = 101,504
#define L_SIG  (L_USL + 8*68*4)               // +2,176  = 103,680
#define LDS_TOTAL (L_SIG + 128)               // 103,808

typedef float f32x4 __attribute__((ext_vector_type(4)));
typedef short s16x4 __attribute__((ext_vector_type(4)));

__device__ __forceinline__ unsigned bfbits(float x) {
    unsigned u = __builtin_bit_cast(unsigned, x);
    unsigned r = u + 0x7FFFu + ((u >> 16) & 1u);
    return r >> 16;
}

__global__ void prep_A(const float* __restrict__ logA, float* __restrict__ AMAT) {
    __shared__ float red[4];
    __shared__ float srow[Qn];
    int row = blockIdx.x, tid = threadIdx.x;
    if (row >= Qn) {  // pad rows 515..543 -> zero
        for (int c = tid; c < QP; c += 256) AMAT[(size_t)row*QP + c] = 0.f;
        return;
    }
    float mx = -1e30f;
    for (int c = tid; c < Qn; c += 256) { float x = logA[(size_t)row*Qn + c]; srow[c] = x; mx = fmaxf(mx, x); }
#pragma unroll
    for (int o = 32; o > 0; o >>= 1) mx = fmaxf(mx, __shfl_xor(mx, o));
    if ((tid & 63) == 0) red[tid >> 6] = mx;
    __syncthreads();
    mx = fmaxf(fmaxf(red[0], red[1]), fmaxf(red[2], red[3]));
    __syncthreads();
    float sm = 0.f;
    for (int c = tid; c < Qn; c += 256) sm += __expf(srow[c] - mx);
#pragma unroll
    for (int o = 32; o > 0; o >>= 1) sm += __shfl_xor(sm, o);
    if ((tid & 63) == 0) red[tid >> 6] = sm;
    __syncthreads();
    float inv = 1.f / (red[0] + red[1] + red[2] + red[3]);
    for (int c = tid; c < QP; c += 256)
        AMAT[(size_t)row*QP + c] = (c < Qn) ? __expf(srow[c] - mx) * inv : 0.f;
}

__global__ void prep_init(const float* __restrict__ il, float* __restrict__ INITD) {
    __shared__ float red[4];
    __shared__ float srow[Qn];
    int tid = threadIdx.x;
    float mx = -1e30f;
    for (int c = tid; c < Qn; c += 256) { float x = il[c]; srow[c] = x; mx = fmaxf(mx, x); }
#pragma unroll
    for (int o = 32; o > 0; o >>= 1) mx = fmaxf(mx, __shfl_xor(mx, o));
    if ((tid & 63) == 0) red[tid >> 6] = mx;
    __syncthreads();
    mx = fmaxf(fmaxf(red[0], red[1]), fmaxf(red[2], red[3]));
    __syncthreads();
    float sm = 0.f;
    for (int c = tid; c < Qn; c += 256) sm += __expf(srow[c] - mx);
#pragma unroll
    for (int o = 32; o > 0; o >>= 1) sm += __shfl_xor(sm, o);
    if ((tid & 63) == 0) red[tid >> 6] = sm;
    __syncthreads();
    float inv = 1.f / (red[0] + red[1] + red[2] + red[3]);
    for (int c = tid; c < QP; c += 256)
        INITD[c] = (c < Qn) ? __expf(srow[c] - mx) * inv : 0.f;
}

__global__ void __launch_bounds__(256, 1)
hmm_fwd(const float* __restrict__ E, const float* __restrict__ AMAT,
        const float* __restrict__ INITD, float* __restrict__ out,
        float* __restrict__ ubuf, float* __restrict__ psum,
        unsigned* __restrict__ flags)
{
    extern __shared__ char smem[];
    uint2*  frag   = (uint2*)(smem + L_FRAG);                  // [NT*KT*64]
    unsigned short* ustage = (unsigned short*)(smem + L_UST);  // [16][USTR]
    float*  usl    = (float*)(smem + L_USL);                   // [8][68]
    float*  invs   = (float*)(smem + L_SIG);                   // [8]
    float*  lsig   = invs + 8;                                 // [8]

    const int tid  = threadIdx.x;
    const int lane = tid & 63;
    const int wv   = tid >> 6;
    const int bid  = blockIdx.x;
    const int g    = bid & 31;     // group
    const int j    = bid >> 5;     // column-slice index within group
    const int b0   = g * 8;
    const int q0   = j * NSL;      // original col base
    const int q0p  = j * 66;       // padded col base

    // ---- one-time: pack A column-slice into LDS as MFMA B-fragments (padded-k space) ----
    for (int f = tid; f < NT*KT*64; f += 256) {
        int tile = f >> 6, l = f & 63;
        int nt = tile / KT, kt = tile - nt*KT;
        int col = q0 + nt*16 + (l & 15);
        int kb  = kt*16 + ((l >> 4) << 2);
        float v[4];
#pragma unroll
        for (int i = 0; i < 4; ++i) {
            int pk_ = kb + i;
            int jr = pk_ / 66, rr = pk_ - jr*66;
            int qrow = (rr < 65) ? (jr*65 + rr) : -1;
            v[i] = (qrow >= 0 && col < QP) ? AMAT[(size_t)qrow*QP + col] : 0.f;
        }
        uint2 pk;
        pk.x = bfbits(v[0]) | (bfbits(v[1]) << 16);
        pk.y = bfbits(v[2]) | (bfbits(v[3]) << 16);
        frag[f] = pk;
    }
    for (int i = tid; i < 16*(USTR/2); i += 256) ((unsigned*)ustage)[i] = 0u;
    float llreg = 0.f;
    float ur0[9], ur1[9];
    __syncthreads();

    // ---- per-thread E-offset map matching MFMA D-lane layout ----
    const int ntn = (wv == 0) ? 2 : 1;
    const int nts0 = wv;
    int eoff[2][4];
#pragma unroll
    for (int sl = 0; sl < 2; ++sl) {
#pragma unroll
        for (int r = 0; r < 4; ++r) {
            int nt  = sl ? 4 : nts0;
            int row = ((lane >> 4) << 2) + r;
            int col = nt*16 + (lane & 15);
            int q   = q0 + col;
            bool ok = (lane < 32) && (col < NSL) && (q < Qn) && (sl < ntn);
            eoff[sl][r] = ok ? ((b0 + row)*Qn + q) : -1;
        }
    }

    auto rowsum_store = [&](int wb, int snum) {
        int half = lane >> 5, c = lane & 31;
        int row = wv*2 + half;
        float v = usl[row*68 + c] + usl[row*68 + c + 32];
        if (c == 0) v += usl[row*68 + 64];
#pragma unroll
        for (int o = 16; o > 0; o >>= 1) v += __shfl_xor(v, o);
        if (c == 0)
            __hip_atomic_store(&psum[(((size_t)wb*NGRP + g)*8 + row)*8 + j], v,
                               __ATOMIC_RELAXED, __HIP_MEMORY_SCOPE_AGENT);
        float* ubr = ubuf + (((size_t)wb*NGRP + g)*8)*QP2 + q0p;
        for (int p = tid; p < 8*33; p += 256) {
            int rw = p/33, cl = p - rw*33;
            float a0 = usl[rw*68 + 2*cl];
            float a1 = (2*cl + 1 < NSL) ? usl[rw*68 + 2*cl + 1] : 0.f;
            uint64_t pk = (uint64_t)__builtin_bit_cast(unsigned, a0)
                        | ((uint64_t)__builtin_bit_cast(unsigned, a1) << 32);
            __hip_atomic_store((uint64_t*)(ubr + rw*QP2 + 2*cl), pk,
                               __ATOMIC_RELAXED, __HIP_MEMORY_SCOPE_AGENT);
        }
        __syncthreads();   // drains all vmem stores of the block before flag
        if (tid == 0)
            __hip_atomic_store(&flags[((unsigned)g*NBLK + j)*16], (unsigned)(snum + 1),
                               __ATOMIC_RELAXED, __HIP_MEMORY_SCOPE_AGENT);
    };

    auto spin_wait = [&](unsigned target) {
        if (tid < 8) {
            const unsigned* fp = flags + ((unsigned)g*NBLK + tid)*16;
            while (__hip_atomic_load(fp, __ATOMIC_RELAXED, __HIP_MEMORY_SCOPE_AGENT) < target)
                __builtin_amdgcn_s_sleep(1);
        }
        __syncthreads();
    };

    auto head_phase = [&](int rb, bool do_stage) {
        float ss = 0.f;
        if (tid < 8) {
            const float* pp = psum + (((size_t)rb*NGRP + g)*8 + tid)*8;
#pragma unroll
            for (int jj = 0; jj < 8; ++jj)
                ss += __hip_atomic_load(&pp[jj], __ATOMIC_RELAXED, __HIP_MEMORY_SCOPE_AGENT);
        }
        const float* ub = ubuf + (((size_t)rb*NGRP + g)*8)*QP2;
#pragma unroll
        for (int it = 0; it < 9; ++it) {
            int p = tid + it*256;
            bool ok = p < 8*264;
            int row = p / 264, kp = p - row*264;
            const uint64_t* ap = (const uint64_t*)(ub + (ok ? (row*QP2 + kp*2) : 0));
            uint64_t w = __hip_atomic_load(ap, __ATOMIC_RELAXED, __HIP_MEMORY_SCOPE_AGENT);
            ur0[it] = ok ? __builtin_bit_cast(float, (unsigned)(w & 0xffffffffu)) : 0.f;
            ur1[it] = ok ? __builtin_bit_cast(float, (unsigned)(w >> 32)) : 0.f;
        }
        if (tid < 8) {
            float ls = __logf(ss);
            invs[tid] = 1.f / ss;
            lsig[tid] = ls;
            llreg += ls;
        }
        __syncthreads();
        if (do_stage) {
#pragma unroll
            for (int it = 0; it < 9; ++it) {
                int p = tid + it*256;
                if (p < 8*264) {
                    int row = p / 264, kp = p - row*264;
                    float iv = invs[row];
                    ((unsigned*)ustage)[row*(USTR/2) + kp] =
                        bfbits(ur0[it]*iv) | (bfbits(ur1[it]*iv) << 16);
                }
            }
            __syncthreads();
        }
    };

    auto emit_outputs = [&](int tOut) {
        if (tid < 8 && j == 0)
            out[((size_t)(b0 + tid)*Tn + tOut)*OQ + Qn] = llreg;
#pragma unroll
        for (int it = 0; it < 9; ++it) {
            int p = tid + it*256;
            if (p < 8*264) {
                int row = p / 264, kp = p - row*264;
                int rr = kp*2 - q0p;
                if (rr >= 0 && rr < NSL) {
                    float ls = lsig[row];
                    int q = q0 + rr;
                    if (q < Qn)
                        out[((size_t)(b0+row)*Tn + tOut)*OQ + q]     = __logf(ur0[it]) - ls;
                    if (rr + 1 < NSL && q + 1 < Qn)
                        out[((size_t)(b0+row)*Tn + tOut)*OQ + q + 1] = __logf(ur1[it]) - ls;
                }
            }
        }
    };

    // ---- t = 0 : u0 = max(E0,eps) * max(init,eps) ----
    {
        for (int p = tid; p < 8*NSL; p += 256) {
            int row = p / NSL, col = p - row*NSL;
            int q = q0 + col;
            float uv = 0.f;
            if (q < Qn) {
                float e  = fmaxf(E[(size_t)(b0+row)*Qn + q], EPSc);
                float r0 = fmaxf(INITD[q], EPSc);
                uv = e * r0;
            }
            usl[row*68 + col] = uv;
        }
        __syncthreads();
        rowsum_store(0, 0);
    }

    // ---- main loop ----
    for (int s = 1; s < Tn; ++s) {
        // prefetch E_s (issued before the spin so HBM latency hides under it)
        float ev[2][4];
        size_t ebase = (size_t)s * Bn * Qn;
#pragma unroll
        for (int sl = 0; sl < 2; ++sl)
#pragma unroll
            for (int r = 0; r < 4; ++r)
                ev[sl][r] = (eoff[sl][r] >= 0) ? E[ebase + eoff[sl][r]] : 0.f;

        spin_wait((unsigned)s);
        head_phase((s-1) & 1, true);

        // MFMA: R-chunk = a_{s-1} (16xK, rows 8..15 zero) @ Aslice (KxN), split-K x2
        f32x4 a0a = {0.f,0.f,0.f,0.f}, a0b = {0.f,0.f,0.f,0.f};
        f32x4 a1a = {0.f,0.f,0.f,0.f}, a1b = {0.f,0.f,0.f,0.f};
        {
            const unsigned short* urow = ustage + (lane & 15)*USTR + ((lane >> 4) << 2);
            const uint2* f0 = frag + (size_t)(nts0*KT)*64 + lane;
            const uint2* f1 = frag + (size_t)(4*KT)*64 + lane;
#pragma unroll 2
            for (int kt = 0; kt < KTA; ++kt) {
                s16x4 af = __builtin_bit_cast(s16x4, *(const uint2*)(urow + kt*16));
                a0a = __builtin_amdgcn_mfma_f32_16x16x16bf16_1k(af, __builtin_bit_cast(s16x4, f0[kt*64]), a0a, 0, 0, 0);
                if (ntn == 2)
                    a1a = __builtin_amdgcn_mfma_f32_16x16x16bf16_1k(af, __builtin_bit_cast(s16x4, f1[kt*64]), a1a, 0, 0, 0);
                int k2 = kt + KTA;
                if (k2 < KT) {
                    s16x4 af2 = __builtin_bit_cast(s16x4, *(const uint2*)(urow + k2*16));
                    a0b = __builtin_amdgcn_mfma_f32_16x16x16bf16_1k(af2, __builtin_bit_cast(s16x4, f0[k2*64]), a0b, 0, 0, 0);
                    if (ntn == 2)
                        a1b = __builtin_amdgcn_mfma_f32_16x16x16bf16_1k(af2, __builtin_bit_cast(s16x4, f1[k2*64]), a1b, 0, 0, 0);
                }
            }
        }
        // epilogue: u_s = max(E,eps) * max(R,eps)
        if (lane < 32) {
#pragma unroll
            for (int r = 0; r < 4; ++r) {
                int row = ((lane >> 4) << 2) + r;
                {
                    int col = nts0*16 + (lane & 15);
                    if (col < NSL) {
                        float R = fmaxf(a0a[r] + a0b[r], EPSc);
                        int q = q0 + col;
                        usl[row*68 + col] = (q < Qn) ? fmaxf(ev[0][r], EPSc) * R : 0.f;
                    }
                }
                if (ntn == 2) {
                    int col = 64 + (lane & 15);
                    if (col < NSL) {
                        float R = fmaxf(a1a[r] + a1b[r], EPSc);
                        int q = q0 + col;
                        usl[row*68 + col] = (q < Qn) ? fmaxf(ev[1][r], EPSc) * R : 0.f;
                    }
                }
            }
        }
        __syncthreads();
        rowsum_store(s & 1, s);

        // off the inter-block critical path: write log-outputs for t = s-1
        emit_outputs(s - 1);
    }

    // ---- tail: emit outputs for t = 511 ----
    spin_wait((unsigned)Tn);
    head_phase((Tn-1) & 1, false);
    emit_outputs(Tn - 1);
}

extern "C" void kernel_launch(void* const* d_in, const int* in_sizes, int n_in,
                              void* d_out, int out_size, void* d_ws, size_t ws_size,
                              hipStream_t stream) {
    (void)in_sizes; (void)n_in; (void)out_size;
    if (ws_size < (size_t)WS_TOTAL) return;

    const float* E    = (const float*)d_in[0];
    const float* logA = (const float*)d_in[1];
    const float* il   = (const float*)d_in[2];
    float* out = (float*)d_out;
    char*  ws  = (char*)d_ws;

    float*    AMAT  = (float*)(ws + WS_AMAT);
    float*    INITD = (float*)(ws + WS_INIT);
    float*    ubuf  = (float*)(ws + WS_UBUF);
    float*    psum  = (float*)(ws + WS_PSUM);
    unsigned* flags = (unsigned*)(ws + WS_FLAG);

    // zero exchange buffers + flags (must be 0 at every launch/replay)
    hipMemsetAsync(ws + WS_UBUF, 0, WS_TOTAL - WS_UBUF, stream);

    prep_A<<<544, 256, 0, stream>>>(logA, AMAT);
    prep_init<<<1, 256, 0, stream>>>(il, INITD);

    static_assert(LDS_TOTAL < 160*1024, "LDS budget");
    hipFuncSetAttribute(reinterpret_cast<const void*>(hmm_fwd),
                        hipFuncAttributeMaxDynamicSharedMemorySize, LDS_TOTAL);
    hmm_fwd<<<256, 256, LDS_TOTAL, stream>>>(E, AMAT, INITD, out, ubuf, psum, flags);
}